// Round 14
// baseline (608.522 us; speedup 1.0000x reference)
//
#include <hip/hip_runtime.h>
#include <hip/hip_cooperative_groups.h>
#include <math.h>

namespace cg = cooperative_groups;

// ---------------------------------------------------------------------------
// GCNEncoder: 3 stacked GCNConv layers (symmetric norm, self-loops) + ReLU.
//   R14: (a) math reverted to R12 (fp32 intermediates; R13's bf16 aggregates
//       regressed 2x -- instruction-bound + tail imbalance); (b) whole CSR
//       build fused into ONE cooperative kernel (zero+prepW+normalize ->
//       hist -> scan -> offsets -> fill) with grid.sync() between phases:
//       11 -> 6 launches (~45us of replay gaps = dur - Sum(dispatch work)).
//   Carried: bf16-split MFMA transforms, XCD-partitioned hist/fill phases,
//   2-node edge-group aggregates, fused W3.
// ---------------------------------------------------------------------------

#define FULL_GRID 2048
#define CSR_GRID 1024
#define PARTS 8

typedef const __attribute__((address_space(1))) void* gas_ptr;
typedef __attribute__((address_space(3))) void* las_ptr;
typedef __attribute__((ext_vector_type(8))) short bf16x8;
typedef __attribute__((ext_vector_type(4))) float f32x4;

__device__ __forceinline__ void gld16(const void* g, void* l) {
  __builtin_amdgcn_global_load_lds((gas_ptr)g, (las_ptr)l, 16, 0, 0);
}

__device__ __forceinline__ unsigned short f2bf(float f) {  // RNE fp32->bf16
  unsigned int u = __float_as_uint(f);
  u += 0x7FFF + ((u >> 16) & 1);
  return (unsigned short)(u >> 16);
}
__device__ __forceinline__ float bf2f(unsigned short h) {
  return __uint_as_float(((unsigned int)h) << 16);
}

// One cooperative kernel: A) zero counts + prepW + normalize edges ->
// B) XCD-partitioned hist -> C) chunk scan -> E) offsets/cursor/dinv ->
// F) XCD-partitioned fill.
__global__ __launch_bounds__(256, 4) void k_csr(
    int* __restrict__ counts, int n4, const void* __restrict__ eraw, int E,
    int* __restrict__ srcn, int* __restrict__ dstn,
    const float* __restrict__ W1, const float* __restrict__ W2,
    short* __restrict__ Wh1, short* __restrict__ Wl1,
    short* __restrict__ Wh2, short* __restrict__ Wl2,
    int* __restrict__ scanned, int* __restrict__ partials,
    int* __restrict__ offsets, int* __restrict__ cursor,
    float* __restrict__ dinv, int* __restrict__ elist, int N) {
  cg::grid_group grid = cg::this_grid();
  const int tid = threadIdx.x;
  const int b = blockIdx.x;

  __shared__ int sm[256];
  __shared__ int ss[256];
  __shared__ int ps[1024];

  // ---- Phase A: zero counts + prep W frags + normalize edges ----
  if (b < 8) {  // W fragment prep (hi/lo bf16, MFMA B-frag order)
    const int t = b * 256 + tid;
    const int stride = 8 * 256;
    for (int q = t; q < 4 * 4 * 64 * 8; q += stride) {  // W1: KT=4, NT=4
      const int e = q & 7, lane = (q >> 3) & 63, nt = (q >> 9) & 3, kt = q >> 11;
      const int k = kt * 32 + (lane >> 4) * 8 + e;
      const int nn = nt * 16 + (lane & 15);
      const float f = W1[k * 64 + nn];
      const unsigned short h = f2bf(f);
      Wh1[q] = (short)h;
      Wl1[q] = (short)f2bf(f - bf2f(h));
    }
    for (int q = t; q < 2 * 2 * 64 * 8; q += stride) {  // W2: KT=2, NT=2
      const int e = q & 7, lane = (q >> 3) & 63, nt = (q >> 9) & 1, kt = q >> 10;
      const int k = kt * 32 + (lane >> 4) * 8 + e;
      const int nn = nt * 16 + (lane & 15);
      const float f = W2[k * 32 + nn];
      const unsigned short h = f2bf(f);
      Wh2[q] = (short)h;
      Wl2[q] = (short)f2bf(f - bf2f(h));
    }
  } else {
    int i = (b - 8) * 256 + tid;  // zero counts
    const int zstride = (CSR_GRID - 8) * 256;
    int4* p4 = (int4*)counts;
    for (; i < n4; i += zstride) p4[i] = make_int4(0, 0, 0, 0);
    // per-block dtype detect: odd 32-bit words of an int64 prefix are zero
    const unsigned int* words = (const unsigned int*)eraw;
    sm[tid] = (words[tid * 2 + 1] == 0u) ? 1 : 0;
    __syncthreads();
    for (int off = 128; off > 0; off >>= 1) {
      if (tid < off) sm[tid] += sm[tid + off];
      __syncthreads();
    }
    const int is64 = sm[0] > 128;
    i = (b - 8) * 256 + tid;  // normalize edges -> int32
    if (is64) {
      const long long* e = (const long long*)eraw;
      for (; i < E; i += zstride) {
        srcn[i] = (int)e[i];
        dstn[i] = (int)e[(long long)E + i];
      }
    } else {
      const int* e = (const int*)eraw;
      for (; i < E; i += zstride) {
        srcn[i] = e[i];
        dstn[i] = e[E + i];
      }
    }
  }
  grid.sync();

  // ---- Phase B: XCD-partitioned histogram ----
  {
    const int part = b & (PARTS - 1);
    const int lo = (int)((long long)N * part / PARTS);
    const int hi = (int)((long long)N * (part + 1) / PARTS);
    int i = (b >> 3) * 256 + tid;
    const int stride = (CSR_GRID >> 3) * 256;
    for (; i < E; i += stride) {
      const int d = dstn[i];
      if (d >= lo && d < hi) atomicAdd(&counts[d], 1);
    }
  }
  grid.sync();

  // ---- Phase C: per-1024-chunk exclusive scan (4 elems/thread) ----
  {
    const int NBLK = (N + 1023) >> 10;
    for (int blk = b; blk < NBLK; blk += CSR_GRID) {
      const int base = blk * 1024 + tid * 4;
      int v[4];
      #pragma unroll
      for (int j = 0; j < 4; ++j) v[j] = (base + j < N) ? counts[base + j] : 0;
      const int s = v[0] + v[1] + v[2] + v[3];
      ss[tid] = s;
      __syncthreads();
      for (int off = 1; off < 256; off <<= 1) {
        const int t_ = ss[tid];
        const int u = (tid >= off) ? ss[tid - off] : 0;
        __syncthreads();
        ss[tid] = t_ + u;
        __syncthreads();
      }
      const int incl = ss[tid];
      int excl = incl - s;
      #pragma unroll
      for (int j = 0; j < 4; ++j) {
        if (base + j < N) scanned[base + j] = excl;
        excl += v[j];
      }
      if (tid == 255) partials[blk] = incl;
      __syncthreads();
    }
  }
  grid.sync();

  // ---- Phase E: offsets/cursor/dinv (each block scans partials in LDS) ----
  {
    const int NBLK = (N + 1023) >> 10;
    for (int t2 = tid; t2 < NBLK; t2 += 256) ps[t2] = partials[t2];
    __syncthreads();
    if (tid == 0) {
      int run = 0;
      for (int q = 0; q < NBLK; ++q) { const int v = ps[q]; ps[q] = run; run += v; }
    }
    __syncthreads();
    int i = b * 256 + tid;
    for (; i < N; i += CSR_GRID * 256) {
      const int o = scanned[i] + ps[i >> 10];
      offsets[i] = o;
      cursor[i] = o;
      dinv[i] = rsqrtf((float)counts[i] + 1.0f);  // +1 self-loop
    }
  }
  grid.sync();

  // ---- Phase F: XCD-partitioned fill ----
  {
    const int part = b & (PARTS - 1);
    const int lo = (int)((long long)N * part / PARTS);
    const int hi = (int)((long long)N * (part + 1) / PARTS);
    int i = (b >> 3) * 256 + tid;
    const int stride = (CSR_GRID >> 3) * 256;
    for (; i < E; i += stride) {
      const int d = dstn[i];
      if (d >= lo && d < hi) elist[atomicAdd(&cursor[d], 1)] = srcn[i];
    }
  }
}

// hs = dinv .* (X @ W) via 3-term bf16-split MFMA (R11/R12-proven, fp32 out).
template <int F_IN, int F_OUT>
__global__ __launch_bounds__(256) void k_transform_mfma(
    const float* __restrict__ X, const short* __restrict__ Wh,
    const short* __restrict__ Wl, const float* __restrict__ dinv,
    float* __restrict__ H, int n) {
  constexpr int KT = F_IN / 32;
  constexpr int NT = F_OUT / 16;
  constexpr int K4f = F_IN / 4;
  constexpr int SLOTS = F_IN / 8;
  constexpr int TILE_M = 64;
  constexpr int WFRAG = KT * NT * 64 * 8;
  static_assert((WFRAG * 2) % 1024 == 0, "W segs");

  __shared__ __align__(16) unsigned short Xh[TILE_M * F_IN];
  __shared__ __align__(16) unsigned short Xl[TILE_M * F_IN];
  __shared__ __align__(16) unsigned short Whs[WFRAG];
  __shared__ __align__(16) unsigned short Wls[WFRAG];

  const int tid = threadIdx.x;
  const int lane = tid & 63;
  const int wid = tid >> 6;
  const long long base = (long long)blockIdx.x * TILE_M;

  constexpr int WSEGS = WFRAG * 2 / 1024;
  for (int seg = wid; seg < WSEGS; seg += 4) {
    gld16((const char*)Wh + seg * 1024 + lane * 16, (char*)Whs + seg * 1024);
    gld16((const char*)Wl + seg * 1024 + lane * 16, (char*)Wls + seg * 1024);
  }

  const float4* __restrict__ X4 = (const float4*)X;
  for (int g = tid; g < TILE_M * K4f; g += 256) {
    const int row = g / K4f, c4 = g % K4f;
    float4 v = make_float4(0.f, 0.f, 0.f, 0.f);
    if (base + row < n) v = X4[(base + row) * K4f + c4];
    ushort4 hv, lv;
    hv.x = f2bf(v.x); lv.x = f2bf(v.x - bf2f(hv.x));
    hv.y = f2bf(v.y); lv.y = f2bf(v.y - bf2f(hv.y));
    hv.z = f2bf(v.z); lv.z = f2bf(v.z - bf2f(hv.z));
    hv.w = f2bf(v.w); lv.w = f2bf(v.w - bf2f(hv.w));
    const int slot = (c4 >> 1) ^ (row & (SLOTS - 1));
    const int boff = row * (F_IN * 2) + slot * 16 + (c4 & 1) * 8;
    *(ushort4*)((char*)Xh + boff) = hv;
    *(ushort4*)((char*)Xl + boff) = lv;
  }
  __syncthreads();

  const int arow = lane & 15;
  const int kg = lane >> 4;
  const int lrow = wid * 16 + arow;

  f32x4 acc[NT];
  #pragma unroll
  for (int t = 0; t < NT; ++t) {
    f32x4 z = {0.f, 0.f, 0.f, 0.f};
    acc[t] = z;
  }

  #pragma unroll
  for (int kt = 0; kt < KT; ++kt) {
    const int slot = (kt * 4 + kg) ^ (lrow & (SLOTS - 1));
    const int aoff = lrow * (F_IN * 2) + slot * 16;
    const bf16x8 ah = *(const bf16x8*)((const char*)Xh + aoff);
    const bf16x8 al = *(const bf16x8*)((const char*)Xl + aoff);
    #pragma unroll
    for (int nt = 0; nt < NT; ++nt) {
      const int woff = ((kt * NT + nt) * 64 + lane) * 8;
      const bf16x8 bh = *(const bf16x8*)&Whs[woff];
      const bf16x8 bl = *(const bf16x8*)&Wls[woff];
      acc[nt] = __builtin_amdgcn_mfma_f32_16x16x32_bf16(ah, bh, acc[nt], 0, 0, 0);
      acc[nt] = __builtin_amdgcn_mfma_f32_16x16x32_bf16(ah, bl, acc[nt], 0, 0, 0);
      acc[nt] = __builtin_amdgcn_mfma_f32_16x16x32_bf16(al, bh, acc[nt], 0, 0, 0);
    }
  }

  #pragma unroll
  for (int r = 0; r < 4; ++r) {
    const long long row = base + wid * 16 + kg * 4 + r;
    if (row < n) {
      const float di = dinv[row];
      #pragma unroll
      for (int nt = 0; nt < NT; ++nt)
        H[row * F_OUT + nt * 16 + arow] = di * acc[nt][r];
    }
  }
}

// Edge-group-parallel aggregate, TWO nodes per wave (R12-proven, fp32).
template <int F, bool RELU_OUT, bool FUSE_W3>
__global__ __launch_bounds__(256) void k_agg_vec2(const float* __restrict__ HS,
                                                  const float* __restrict__ dinv,
                                                  const int* __restrict__ offsets,
                                                  const int* __restrict__ counts,
                                                  const int* __restrict__ elist,
                                                  const float* __restrict__ bias,
                                                  const float* __restrict__ W3,
                                                  float* __restrict__ out, int n) {
  constexpr int LPE = F / 4;
  constexpr int EPW = 64 / LPE;
  const int lane = threadIdx.x & 63;
  const int wv = (blockIdx.x * (blockDim.x >> 6)) + (threadIdx.x >> 6);
  const int nwaves = gridDim.x * (blockDim.x >> 6);
  const int g = lane / LPE;
  const int fl = lane % LPE;
  const float4 bf = *(const float4*)&bias[fl * 4];

  float w3a0 = 0.f, w3a1 = 0.f, w3a2 = 0.f, w3a3 = 0.f;
  float w3b0 = 0.f, w3b1 = 0.f, w3b2 = 0.f, w3b3 = 0.f;
  if (FUSE_W3) {
    w3a0 = W3[(fl * 4 + 0) * 2 + 0]; w3b0 = W3[(fl * 4 + 0) * 2 + 1];
    w3a1 = W3[(fl * 4 + 1) * 2 + 0]; w3b1 = W3[(fl * 4 + 1) * 2 + 1];
    w3a2 = W3[(fl * 4 + 2) * 2 + 0]; w3b2 = W3[(fl * 4 + 2) * 2 + 1];
    w3a3 = W3[(fl * 4 + 3) * 2 + 0]; w3b3 = W3[(fl * 4 + 3) * 2 + 1];
  }

  for (long long dA = wv; dA < n; dA += 2ll * nwaves) {
    const long long dB = dA + nwaves;
    const bool hasB = dB < n;
    const float diA = dinv[dA];
    const float diB = hasB ? dinv[dB] : 0.f;
    const int stA = offsets[dA];
    const int cntA = counts[dA];
    const int stB = hasB ? offsets[dB] : 0;
    const int cntB = hasB ? counts[dB] : 0;
    float4 accA = make_float4(0.f, 0.f, 0.f, 0.f);
    float4 accB = make_float4(0.f, 0.f, 0.f, 0.f);
    if (g == 0) accA = *(const float4*)&HS[dA * F + fl * 4];
    if (g == 1 && hasB) accB = *(const float4*)&HS[dB * F + fl * 4];

    const int jmax = cntA > cntB ? cntA : cntB;
    const int cA = cntA > 0 ? cntA - 1 : 0;
    const int cB = cntB > 0 ? cntB - 1 : 0;
    for (int j = 0; j < jmax; j += 2 * EPW) {
      const int e0 = j + g;
      const int e1 = j + EPW + g;
      const int iA0 = elist[stA + (e0 < cntA ? e0 : cA)];
      const int iA1 = elist[stA + (e1 < cntA ? e1 : cA)];
      const int iB0 = elist[stB + (e0 < cntB ? e0 : cB)];
      const int iB1 = elist[stB + (e1 < cntB ? e1 : cB)];
      const float4 vA0 = *(const float4*)&HS[(long long)iA0 * F + fl * 4];
      const float4 vA1 = *(const float4*)&HS[(long long)iA1 * F + fl * 4];
      const float4 vB0 = *(const float4*)&HS[(long long)iB0 * F + fl * 4];
      const float4 vB1 = *(const float4*)&HS[(long long)iB1 * F + fl * 4];
      if (e0 < cntA) {
        accA.x += vA0.x; accA.y += vA0.y; accA.z += vA0.z; accA.w += vA0.w;
      }
      if (e1 < cntA) {
        accA.x += vA1.x; accA.y += vA1.y; accA.z += vA1.z; accA.w += vA1.w;
      }
      if (e0 < cntB) {
        accB.x += vB0.x; accB.y += vB0.y; accB.z += vB0.z; accB.w += vB0.w;
      }
      if (e1 < cntB) {
        accB.x += vB1.x; accB.y += vB1.y; accB.z += vB1.z; accB.w += vB1.w;
      }
    }
    #pragma unroll
    for (int m = LPE; m < 64; m <<= 1) {
      accA.x += __shfl_xor(accA.x, m, 64);
      accA.y += __shfl_xor(accA.y, m, 64);
      accA.z += __shfl_xor(accA.z, m, 64);
      accA.w += __shfl_xor(accA.w, m, 64);
      accB.x += __shfl_xor(accB.x, m, 64);
      accB.y += __shfl_xor(accB.y, m, 64);
      accB.z += __shfl_xor(accB.z, m, 64);
      accB.w += __shfl_xor(accB.w, m, 64);
    }
    float4 rA, rB;
    rA.x = fmaf(diA, accA.x, bf.x); rA.y = fmaf(diA, accA.y, bf.y);
    rA.z = fmaf(diA, accA.z, bf.z); rA.w = fmaf(diA, accA.w, bf.w);
    rB.x = fmaf(diB, accB.x, bf.x); rB.y = fmaf(diB, accB.y, bf.y);
    rB.z = fmaf(diB, accB.z, bf.z); rB.w = fmaf(diB, accB.w, bf.w);
    if (RELU_OUT) {
      rA.x = fmaxf(rA.x, 0.f); rA.y = fmaxf(rA.y, 0.f);
      rA.z = fmaxf(rA.z, 0.f); rA.w = fmaxf(rA.w, 0.f);
      rB.x = fmaxf(rB.x, 0.f); rB.y = fmaxf(rB.y, 0.f);
      rB.z = fmaxf(rB.z, 0.f); rB.w = fmaxf(rB.w, 0.f);
    }
    if (!FUSE_W3) {
      if (g == 0) *(float4*)&out[dA * F + fl * 4] = rA;
      if (g == 1 && hasB) *(float4*)&out[dB * F + fl * 4] = rB;
    } else {
      float tA0 = rA.x * w3a0 + rA.y * w3a1 + rA.z * w3a2 + rA.w * w3a3;
      float tA1 = rA.x * w3b0 + rA.y * w3b1 + rA.z * w3b2 + rA.w * w3b3;
      float tB0 = rB.x * w3a0 + rB.y * w3a1 + rB.z * w3a2 + rB.w * w3a3;
      float tB1 = rB.x * w3b0 + rB.y * w3b1 + rB.z * w3b2 + rB.w * w3b3;
      #pragma unroll
      for (int m = 1; m < LPE; m <<= 1) {
        tA0 += __shfl_xor(tA0, m, 64);
        tA1 += __shfl_xor(tA1, m, 64);
        tB0 += __shfl_xor(tB0, m, 64);
        tB1 += __shfl_xor(tB1, m, 64);
      }
      if (lane == 0) {
        out[dA * 2 + 0] = diA * tA0;
        out[dA * 2 + 1] = diA * tA1;
      }
      if (lane == LPE && hasB) {
        out[dB * 2 + 0] = diB * tB0;
        out[dB * 2 + 1] = diB * tB1;
      }
    }
  }
}

// scalar aggregate for tiny F (layer 3, F=2)
template <int F, bool RELU_OUT>
__global__ __launch_bounds__(256) void k_aggregate(const float* __restrict__ HS,
                                                   const float* __restrict__ dinv,
                                                   const int* __restrict__ offsets,
                                                   const int* __restrict__ counts,
                                                   const int* __restrict__ elist,
                                                   const float* __restrict__ bias,
                                                   float* __restrict__ out, int n) {
  const int f = threadIdx.x % F;
  const int grp = threadIdx.x / F;
  constexpr int GRPS = 256 / F;
  const float bf = bias[f];

  for (long long d = (long long)blockIdx.x * GRPS + grp; d < n;
       d += (long long)gridDim.x * GRPS) {
    const float di = dinv[d];
    float acc = HS[d * F + f];
    const int start = offsets[d];
    const int cnt = counts[d];
    for (int j = 0; j < cnt; j += 8) {
      int idx[8];
      float v[8];
      #pragma unroll
      for (int t = 0; t < 8; ++t) {
        const int jj = (j + t < cnt) ? (j + t) : j;
        idx[t] = elist[start + jj];
      }
      #pragma unroll
      for (int t = 0; t < 8; ++t) v[t] = HS[(long long)idx[t] * F + f];
      #pragma unroll
      for (int t = 0; t < 8; ++t) acc += (j + t < cnt) ? v[t] : 0.f;
    }
    float r = fmaf(di, acc, bf);
    if (RELU_OUT) r = fmaxf(r, 0.f);
    out[d * F + f] = r;
  }
}

extern "C" void kernel_launch(void* const* d_in, const int* in_sizes, int n_in,
                              void* d_out, int out_size, void* d_ws, size_t ws_size,
                              hipStream_t stream) {
  const float* x = (const float*)d_in[0];
  const void* eraw = d_in[1];
  const float* W1 = (const float*)d_in[2];
  const float* b1 = (const float*)d_in[3];
  const float* W2 = (const float*)d_in[4];
  const float* b2 = (const float*)d_in[5];
  const float* W3 = (const float*)d_in[6];
  const float* b3 = (const float*)d_in[7];
  float* out = (float*)d_out;

  const int N = in_sizes[0] / 128;  // 100000
  const int E = in_sizes[1] / 2;    // 600000

  char* ws = (char*)d_ws;
  size_t off = 0;
  auto alloc = [&](size_t bytes) -> char* {
    char* p = ws + off;
    off = (off + bytes + 255) & ~(size_t)255;
    return p;
  };
  int*   counts   = (int*)alloc((size_t)N * 4 + 16);
  int*   scanned  = (int*)alloc((size_t)N * 4);
  int*   partials = (int*)alloc(1024 * 4);
  int*   offsets  = (int*)alloc((size_t)N * 4);
  int*   cursor   = (int*)alloc((size_t)N * 4);
  int*   srcn     = (int*)alloc((size_t)E * 4);
  int*   dstn     = (int*)alloc((size_t)E * 4);
  int*   elist    = (int*)alloc((size_t)E * 4);
  float* dinv     = (float*)alloc((size_t)N * 4);
  short* Wh1      = (short*)alloc(4 * 4 * 64 * 8 * 2);
  short* Wl1      = (short*)alloc(4 * 4 * 64 * 8 * 2);
  short* Wh2      = (short*)alloc(2 * 2 * 64 * 8 * 2);
  short* Wl2      = (short*)alloc(2 * 2 * 64 * 8 * 2);
  float* hbuf     = (float*)alloc((size_t)N * 64 * 4);  // hs1; later hs3 [N,2]
  float* obuf     = (float*)alloc((size_t)N * 64 * 4);  // out1 [N,64]
  float* h2buf    = (float*)alloc((size_t)N * 32 * 4);  // hs2 [N,32]
  (void)ws_size; (void)n_in; (void)out_size;

  // ---- fused CSR build + W pre-pack (cooperative, 5 phases) ----
  int n4 = (N + 3) / 4;
  void* args[] = {(void*)&counts, (void*)&n4, (void*)&eraw, (void*)&E,
                  (void*)&srcn, (void*)&dstn, (void*)&W1, (void*)&W2,
                  (void*)&Wh1, (void*)&Wl1, (void*)&Wh2, (void*)&Wl2,
                  (void*)&scanned, (void*)&partials, (void*)&offsets,
                  (void*)&cursor, (void*)&dinv, (void*)&elist, (void*)&N};
  hipLaunchCooperativeKernel((const void*)k_csr, dim3(CSR_GRID), dim3(256),
                             args, 0, stream);

  // ---- layer 1: hs1 = dinv.*(x@W1); out1 = relu(agg(hs1)) ----
  k_transform_mfma<128, 64><<<(N + 63) / 64, 256, 0, stream>>>(
      x, Wh1, Wl1, dinv, hbuf, N);
  k_agg_vec2<64, true, false><<<FULL_GRID, 256, 0, stream>>>(
      hbuf, dinv, offsets, counts, elist, b1, nullptr, obuf, N);

  // ---- layer 2: hs2 = dinv.*(out1@W2); agg + ReLU + fused W3 -> hs3 ----
  k_transform_mfma<64, 32><<<(N + 63) / 64, 256, 0, stream>>>(
      obuf, Wh2, Wl2, dinv, h2buf, N);
  k_agg_vec2<32, true, true><<<FULL_GRID, 256, 0, stream>>>(
      h2buf, dinv, offsets, counts, elist, b2, W3, hbuf, N);

  // ---- layer 3: agg hs3 + ReLU -> out ----
  k_aggregate<2, true><<<(N + 127) / 128, 256, 0, stream>>>(
      hbuf, dinv, offsets, counts, elist, b3, out, N);
}

// Round 15
// 194.308 us; speedup vs baseline: 3.1317x; 3.1317x over previous
//
#include <hip/hip_runtime.h>
#include <math.h>

// ---------------------------------------------------------------------------
// GCNEncoder: 3 stacked GCNConv layers (symmetric norm, self-loops) + ReLU.
//   R15: R12 base (fp32 intermediates, bf16-split MFMA transforms) +
//     (a) agg1+t2 FUSED: gather out1 rows -> swizzled hi/lo bf16 LDS tile ->
//         in-block MFMA with W2 -> hs2. out1 never hits HBM (51MB saved).
//         Both phases low-VGPR (vs R3's 176-VGPR failure); LDS 24KB.
//     (b) R13-style k_init (normalize fused, per-block dtype detect).
//     9 launches (R12 had 11). R14's cooperative grid.sync (~100us/sync)
//     abandoned -- launch gaps are cheaper than software grid barriers.
// ---------------------------------------------------------------------------

#define FULL_GRID 2048
#define PARTS 8

typedef const __attribute__((address_space(1))) void* gas_ptr;
typedef __attribute__((address_space(3))) void* las_ptr;
typedef __attribute__((ext_vector_type(8))) short bf16x8;
typedef __attribute__((ext_vector_type(4))) float f32x4;

__device__ __forceinline__ void gld16(const void* g, void* l) {
  __builtin_amdgcn_global_load_lds((gas_ptr)g, (las_ptr)l, 16, 0, 0);
}

__device__ __forceinline__ unsigned short f2bf(float f) {  // RNE fp32->bf16
  unsigned int u = __float_as_uint(f);
  u += 0x7FFF + ((u >> 16) & 1);
  return (unsigned short)(u >> 16);
}
__device__ __forceinline__ float bf2f(unsigned short h) {
  return __uint_as_float(((unsigned int)h) << 16);
}

// blocks 0..127: zero counts; 128..159: prep W frags; 160..1183: normalize
// edges (per-block dtype detect on the global prefix -- no flag dependency).
__global__ __launch_bounds__(256) void k_init(int* __restrict__ p, int n4,
                                              const void* __restrict__ eraw, int E,
                                              int* __restrict__ srcn,
                                              int* __restrict__ dstn,
                                              const float* __restrict__ W1,
                                              const float* __restrict__ W2,
                                              short* __restrict__ Wh1,
                                              short* __restrict__ Wl1,
                                              short* __restrict__ Wh2,
                                              short* __restrict__ Wl2) {
  const int b = blockIdx.x;
  if (b < 128) {  // zero counts
    int i = b * blockDim.x + threadIdx.x;
    const int stride = 128 * blockDim.x;
    int4* p4 = (int4*)p;
    for (; i < n4; i += stride) p4[i] = make_int4(0, 0, 0, 0);
    return;
  }
  if (b < 160) {  // W fragment prep (32 blocks)
    const int t = (b - 128) * 256 + threadIdx.x;
    const int stride = 32 * 256;
    for (int q = t; q < 4 * 4 * 64 * 8; q += stride) {  // W1: KT=4, NT=4
      const int e = q & 7, lane = (q >> 3) & 63, nt = (q >> 9) & 3, kt = q >> 11;
      const int k = kt * 32 + (lane >> 4) * 8 + e;
      const int nn = nt * 16 + (lane & 15);
      const float f = W1[k * 64 + nn];
      const unsigned short h = f2bf(f);
      Wh1[q] = (short)h;
      Wl1[q] = (short)f2bf(f - bf2f(h));
    }
    for (int q = t; q < 2 * 2 * 64 * 8; q += stride) {  // W2: KT=2, NT=2
      const int e = q & 7, lane = (q >> 3) & 63, nt = (q >> 9) & 1, kt = q >> 10;
      const int k = kt * 32 + (lane >> 4) * 8 + e;
      const int nn = nt * 16 + (lane & 15);
      const float f = W2[k * 32 + nn];
      const unsigned short h = f2bf(f);
      Wh2[q] = (short)h;
      Wl2[q] = (short)f2bf(f - bf2f(h));
    }
    return;
  }
  // normalize with per-block dtype detect
  __shared__ int sm[256];
  const unsigned int* words = (const unsigned int*)eraw;
  sm[threadIdx.x] = (words[threadIdx.x * 2 + 1] == 0u) ? 1 : 0;
  __syncthreads();
  for (int off = 128; off > 0; off >>= 1) {
    if (threadIdx.x < off) sm[threadIdx.x] += sm[threadIdx.x + off];
    __syncthreads();
  }
  const int is64 = sm[0] > 128;
  const int nb = b - 160;
  int i = nb * 256 + threadIdx.x;
  const int stride = 1024 * 256;
  if (is64) {
    const long long* e = (const long long*)eraw;
    for (; i < E; i += stride) {
      srcn[i] = (int)e[i];
      dstn[i] = (int)e[(long long)E + i];
    }
  } else {
    const int* e = (const int*)eraw;
    for (; i < E; i += stride) {
      srcn[i] = e[i];
      dstn[i] = e[E + i];
    }
  }
}

// XCD-partitioned histogram (partition p = blockIdx&7 -> dst range [lo,hi)).
__global__ __launch_bounds__(256) void k_hist(const int* __restrict__ dstn, int E,
                                              int N, int* __restrict__ counts) {
  const int part = blockIdx.x & (PARTS - 1);
  const int lo = (int)((long long)N * part / PARTS);
  const int hi = (int)((long long)N * (part + 1) / PARTS);
  int i = (blockIdx.x >> 3) * blockDim.x + threadIdx.x;
  const int stride = (gridDim.x >> 3) * blockDim.x;
  for (; i < E; i += stride) {
    const int d = dstn[i];
    if (d >= lo && d < hi) atomicAdd(&counts[d], 1);
  }
}

__global__ __launch_bounds__(1024) void k_scan1(const int* __restrict__ counts,
                                                int* __restrict__ scanned,
                                                int* __restrict__ partials, int n) {
  __shared__ int sm[1024];
  const int i = blockIdx.x * 1024 + threadIdx.x;
  const int v = (i < n) ? counts[i] : 0;
  sm[threadIdx.x] = v;
  __syncthreads();
  for (int off = 1; off < 1024; off <<= 1) {
    int t = sm[threadIdx.x];
    int u = (threadIdx.x >= off) ? sm[threadIdx.x - off] : 0;
    __syncthreads();
    sm[threadIdx.x] = t + u;
    __syncthreads();
  }
  const int inc = sm[threadIdx.x];
  if (i < n) scanned[i] = inc - v;  // exclusive within block
  if (threadIdx.x == 1023) partials[blockIdx.x] = inc;  // block total
}

__global__ __launch_bounds__(256) void k_scan3(const int* __restrict__ scanned,
                                               const int* __restrict__ partials,
                                               int nb,
                                               const int* __restrict__ counts,
                                               int* __restrict__ offsets,
                                               int* __restrict__ cursor,
                                               float* __restrict__ dinv, int n) {
  __shared__ int ps[1024];
  for (int t = threadIdx.x; t < nb; t += 256) ps[t] = partials[t];
  __syncthreads();
  if (threadIdx.x == 0) {
    int run = 0;
    for (int b = 0; b < nb; ++b) { const int v = ps[b]; ps[b] = run; run += v; }
  }
  __syncthreads();
  int i = blockIdx.x * blockDim.x + threadIdx.x;
  const int stride = gridDim.x * blockDim.x;
  for (; i < n; i += stride) {
    const int o = scanned[i] + ps[i >> 10];
    offsets[i] = o;
    cursor[i] = o;
    dinv[i] = rsqrtf((float)counts[i] + 1.0f);  // +1 self-loop
  }
}

// XCD-partitioned fill.
__global__ __launch_bounds__(256) void k_fill(const int* __restrict__ srcn,
                                              const int* __restrict__ dstn, int E,
                                              int N, int* __restrict__ cursor,
                                              int* __restrict__ elist) {
  const int part = blockIdx.x & (PARTS - 1);
  const int lo = (int)((long long)N * part / PARTS);
  const int hi = (int)((long long)N * (part + 1) / PARTS);
  int i = (blockIdx.x >> 3) * blockDim.x + threadIdx.x;
  const int stride = (gridDim.x >> 3) * blockDim.x;
  for (; i < E; i += stride) {
    const int d = dstn[i];
    if (d >= lo && d < hi) elist[atomicAdd(&cursor[d], 1)] = srcn[i];
  }
}

// hs = dinv .* (X @ W) via 3-term bf16-split MFMA (R11/R12-proven, fp32 out).
template <int F_IN, int F_OUT>
__global__ __launch_bounds__(256) void k_transform_mfma(
    const float* __restrict__ X, const short* __restrict__ Wh,
    const short* __restrict__ Wl, const float* __restrict__ dinv,
    float* __restrict__ H, int n) {
  constexpr int KT = F_IN / 32;
  constexpr int NT = F_OUT / 16;
  constexpr int K4f = F_IN / 4;
  constexpr int SLOTS = F_IN / 8;
  constexpr int TILE_M = 64;
  constexpr int WFRAG = KT * NT * 64 * 8;
  static_assert((WFRAG * 2) % 1024 == 0, "W segs");

  __shared__ __align__(16) unsigned short Xh[TILE_M * F_IN];
  __shared__ __align__(16) unsigned short Xl[TILE_M * F_IN];
  __shared__ __align__(16) unsigned short Whs[WFRAG];
  __shared__ __align__(16) unsigned short Wls[WFRAG];

  const int tid = threadIdx.x;
  const int lane = tid & 63;
  const int wid = tid >> 6;
  const long long base = (long long)blockIdx.x * TILE_M;

  constexpr int WSEGS = WFRAG * 2 / 1024;
  for (int seg = wid; seg < WSEGS; seg += 4) {
    gld16((const char*)Wh + seg * 1024 + lane * 16, (char*)Whs + seg * 1024);
    gld16((const char*)Wl + seg * 1024 + lane * 16, (char*)Wls + seg * 1024);
  }

  const float4* __restrict__ X4 = (const float4*)X;
  for (int g = tid; g < TILE_M * K4f; g += 256) {
    const int row = g / K4f, c4 = g % K4f;
    float4 v = make_float4(0.f, 0.f, 0.f, 0.f);
    if (base + row < n) v = X4[(base + row) * K4f + c4];
    ushort4 hv, lv;
    hv.x = f2bf(v.x); lv.x = f2bf(v.x - bf2f(hv.x));
    hv.y = f2bf(v.y); lv.y = f2bf(v.y - bf2f(hv.y));
    hv.z = f2bf(v.z); lv.z = f2bf(v.z - bf2f(hv.z));
    hv.w = f2bf(v.w); lv.w = f2bf(v.w - bf2f(hv.w));
    const int slot = (c4 >> 1) ^ (row & (SLOTS - 1));
    const int boff = row * (F_IN * 2) + slot * 16 + (c4 & 1) * 8;
    *(ushort4*)((char*)Xh + boff) = hv;
    *(ushort4*)((char*)Xl + boff) = lv;
  }
  __syncthreads();

  const int arow = lane & 15;
  const int kg = lane >> 4;
  const int lrow = wid * 16 + arow;

  f32x4 acc[NT];
  #pragma unroll
  for (int t = 0; t < NT; ++t) {
    f32x4 z = {0.f, 0.f, 0.f, 0.f};
    acc[t] = z;
  }

  #pragma unroll
  for (int kt = 0; kt < KT; ++kt) {
    const int slot = (kt * 4 + kg) ^ (lrow & (SLOTS - 1));
    const int aoff = lrow * (F_IN * 2) + slot * 16;
    const bf16x8 ah = *(const bf16x8*)((const char*)Xh + aoff);
    const bf16x8 al = *(const bf16x8*)((const char*)Xl + aoff);
    #pragma unroll
    for (int nt = 0; nt < NT; ++nt) {
      const int woff = ((kt * NT + nt) * 64 + lane) * 8;
      const bf16x8 bh = *(const bf16x8*)&Whs[woff];
      const bf16x8 bl = *(const bf16x8*)&Wls[woff];
      acc[nt] = __builtin_amdgcn_mfma_f32_16x16x32_bf16(ah, bh, acc[nt], 0, 0, 0);
      acc[nt] = __builtin_amdgcn_mfma_f32_16x16x32_bf16(ah, bl, acc[nt], 0, 0, 0);
      acc[nt] = __builtin_amdgcn_mfma_f32_16x16x32_bf16(al, bh, acc[nt], 0, 0, 0);
    }
  }

  #pragma unroll
  for (int r = 0; r < 4; ++r) {
    const long long row = base + wid * 16 + kg * 4 + r;
    if (row < n) {
      const float di = dinv[row];
      #pragma unroll
      for (int nt = 0; nt < NT; ++nt)
        H[row * F_OUT + nt * 16 + arow] = di * acc[nt][r];
    }
  }
}

// FUSED agg1 + transform2. Block = 64 dst nodes / 4 waves.
// Phase 1: edge-group gather (LPE=16 lanes x float4 slice, 8 edges in
//   flight) -> out1 row = relu(b1 + dinv*(self + sum)); hi/lo bf16 into
//   swizzled LDS (out1 never hits HBM).
// Phase 2: hs2 = dinv .* (out1 @ W2) via 3-term bf16-split MFMA.
__global__ __launch_bounds__(256) void k_agg1_t2(
    const float* __restrict__ HS1, const float* __restrict__ dinv,
    const int* __restrict__ offsets, const int* __restrict__ counts,
    const int* __restrict__ elist, const float* __restrict__ b1,
    const short* __restrict__ Wh, const short* __restrict__ Wl,
    float* __restrict__ H2, int n) {
  constexpr int WFRAG = 2 * 2 * 64 * 8;  // 2048 shorts
  __shared__ __align__(16) unsigned short Xh[64 * 64];
  __shared__ __align__(16) unsigned short Xl[64 * 64];
  __shared__ __align__(16) unsigned short Whs[WFRAG];
  __shared__ __align__(16) unsigned short Wls[WFRAG];

  const int tid = threadIdx.x;
  const int lane = tid & 63;
  const int wid = tid >> 6;
  const long long base = (long long)blockIdx.x * 64;

  // stage W2 fragments (4 x 1KB segs each; wave w stages seg w)
  gld16((const char*)Wh + wid * 1024 + lane * 16, (char*)Whs + wid * 1024);
  gld16((const char*)Wl + wid * 1024 + lane * 16, (char*)Wls + wid * 1024);

  // ---- phase 1: gather out1 rows -> LDS ----
  const int g = lane >> 4;    // edge slot 0..3
  const int fl = lane & 15;   // float4 slice index
  const float4 bf = *(const float4*)&b1[fl * 4];

  for (int t = 0; t < 16; ++t) {
    const int rl = wid * 16 + t;
    const long long d = base + rl;
    float4 r = make_float4(0.f, 0.f, 0.f, 0.f);
    if (d < n) {
      const float di = dinv[d];
      float4 acc = make_float4(0.f, 0.f, 0.f, 0.f);
      if (g == 0) acc = *(const float4*)&HS1[d * 64 + fl * 4];  // self (scaled)
      const int start = offsets[d];
      const int cnt = counts[d];
      const int cl = cnt > 0 ? cnt - 1 : 0;
      for (int j = 0; j < cnt; j += 8) {
        const int e0 = j + g;
        const int e1 = j + 4 + g;
        const int i0 = elist[start + (e0 < cnt ? e0 : cl)];
        const int i1 = elist[start + (e1 < cnt ? e1 : cl)];
        const float4 v0 = *(const float4*)&HS1[(long long)i0 * 64 + fl * 4];
        const float4 v1 = *(const float4*)&HS1[(long long)i1 * 64 + fl * 4];
        if (e0 < cnt) {
          acc.x += v0.x; acc.y += v0.y; acc.z += v0.z; acc.w += v0.w;
        }
        if (e1 < cnt) {
          acc.x += v1.x; acc.y += v1.y; acc.z += v1.z; acc.w += v1.w;
        }
      }
      #pragma unroll
      for (int m = 16; m < 64; m <<= 1) {
        acc.x += __shfl_xor(acc.x, m, 64);
        acc.y += __shfl_xor(acc.y, m, 64);
        acc.z += __shfl_xor(acc.z, m, 64);
        acc.w += __shfl_xor(acc.w, m, 64);
      }
      r.x = fmaxf(fmaf(di, acc.x, bf.x), 0.f);
      r.y = fmaxf(fmaf(di, acc.y, bf.y), 0.f);
      r.z = fmaxf(fmaf(di, acc.z, bf.z), 0.f);
      r.w = fmaxf(fmaf(di, acc.w, bf.w), 0.f);
    }
    if (g == 0) {  // hi/lo bf16, swizzled 16B slots (slot = (fl>>1)^(row&7))
      ushort4 hv, lv;
      hv.x = f2bf(r.x); lv.x = f2bf(r.x - bf2f(hv.x));
      hv.y = f2bf(r.y); lv.y = f2bf(r.y - bf2f(hv.y));
      hv.z = f2bf(r.z); lv.z = f2bf(r.z - bf2f(hv.z));
      hv.w = f2bf(r.w); lv.w = f2bf(r.w - bf2f(hv.w));
      const int boff = rl * 128 + (((fl >> 1) ^ (rl & 7)) * 16) + (fl & 1) * 8;
      *(ushort4*)((char*)Xh + boff) = hv;
      *(ushort4*)((char*)Xl + boff) = lv;
    }
  }
  __syncthreads();  // LDS writes + W staging (vmcnt) drained

  // ---- phase 2: MFMA out1 @ W2 -> hs2 ----
  const int arow = lane & 15;
  const int kg = lane >> 4;
  const int lrow = wid * 16 + arow;

  f32x4 acc[2];
  #pragma unroll
  for (int t = 0; t < 2; ++t) {
    f32x4 z = {0.f, 0.f, 0.f, 0.f};
    acc[t] = z;
  }

  #pragma unroll
  for (int kt = 0; kt < 2; ++kt) {
    const int slot = (kt * 4 + kg) ^ (lrow & 7);
    const bf16x8 ah = *(const bf16x8*)&Xh[lrow * 64 + slot * 8];
    const bf16x8 al = *(const bf16x8*)&Xl[lrow * 64 + slot * 8];
    #pragma unroll
    for (int nt = 0; nt < 2; ++nt) {
      const int woff = ((kt * 2 + nt) * 64 + lane) * 8;
      const bf16x8 bh = *(const bf16x8*)&Whs[woff];
      const bf16x8 bl = *(const bf16x8*)&Wls[woff];
      acc[nt] = __builtin_amdgcn_mfma_f32_16x16x32_bf16(ah, bh, acc[nt], 0, 0, 0);
      acc[nt] = __builtin_amdgcn_mfma_f32_16x16x32_bf16(ah, bl, acc[nt], 0, 0, 0);
      acc[nt] = __builtin_amdgcn_mfma_f32_16x16x32_bf16(al, bh, acc[nt], 0, 0, 0);
    }
  }

  #pragma unroll
  for (int r = 0; r < 4; ++r) {
    const long long row = base + wid * 16 + kg * 4 + r;
    if (row < n) {
      const float di = dinv[row];
      H2[row * 32 + 0 * 16 + arow] = di * acc[0][r];
      H2[row * 32 + 1 * 16 + arow] = di * acc[1][r];
    }
  }
}

// Edge-group-parallel aggregate, TWO nodes per wave (R12-proven, fp32).
template <int F, bool RELU_OUT, bool FUSE_W3>
__global__ __launch_bounds__(256) void k_agg_vec2(const float* __restrict__ HS,
                                                  const float* __restrict__ dinv,
                                                  const int* __restrict__ offsets,
                                                  const int* __restrict__ counts,
                                                  const int* __restrict__ elist,
                                                  const float* __restrict__ bias,
                                                  const float* __restrict__ W3,
                                                  float* __restrict__ out, int n) {
  constexpr int LPE = F / 4;
  constexpr int EPW = 64 / LPE;
  const int lane = threadIdx.x & 63;
  const int wv = (blockIdx.x * (blockDim.x >> 6)) + (threadIdx.x >> 6);
  const int nwaves = gridDim.x * (blockDim.x >> 6);
  const int g = lane / LPE;
  const int fl = lane % LPE;
  const float4 bf = *(const float4*)&bias[fl * 4];

  float w3a0 = 0.f, w3a1 = 0.f, w3a2 = 0.f, w3a3 = 0.f;
  float w3b0 = 0.f, w3b1 = 0.f, w3b2 = 0.f, w3b3 = 0.f;
  if (FUSE_W3) {
    w3a0 = W3[(fl * 4 + 0) * 2 + 0]; w3b0 = W3[(fl * 4 + 0) * 2 + 1];
    w3a1 = W3[(fl * 4 + 1) * 2 + 0]; w3b1 = W3[(fl * 4 + 1) * 2 + 1];
    w3a2 = W3[(fl * 4 + 2) * 2 + 0]; w3b2 = W3[(fl * 4 + 2) * 2 + 1];
    w3a3 = W3[(fl * 4 + 3) * 2 + 0]; w3b3 = W3[(fl * 4 + 3) * 2 + 1];
  }

  for (long long dA = wv; dA < n; dA += 2ll * nwaves) {
    const long long dB = dA + nwaves;
    const bool hasB = dB < n;
    const float diA = dinv[dA];
    const float diB = hasB ? dinv[dB] : 0.f;
    const int stA = offsets[dA];
    const int cntA = counts[dA];
    const int stB = hasB ? offsets[dB] : 0;
    const int cntB = hasB ? counts[dB] : 0;
    float4 accA = make_float4(0.f, 0.f, 0.f, 0.f);
    float4 accB = make_float4(0.f, 0.f, 0.f, 0.f);
    if (g == 0) accA = *(const float4*)&HS[dA * F + fl * 4];
    if (g == 1 && hasB) accB = *(const float4*)&HS[dB * F + fl * 4];

    const int jmax = cntA > cntB ? cntA : cntB;
    const int cA = cntA > 0 ? cntA - 1 : 0;
    const int cB = cntB > 0 ? cntB - 1 : 0;
    for (int j = 0; j < jmax; j += 2 * EPW) {
      const int e0 = j + g;
      const int e1 = j + EPW + g;
      const int iA0 = elist[stA + (e0 < cntA ? e0 : cA)];
      const int iA1 = elist[stA + (e1 < cntA ? e1 : cA)];
      const int iB0 = elist[stB + (e0 < cntB ? e0 : cB)];
      const int iB1 = elist[stB + (e1 < cntB ? e1 : cB)];
      const float4 vA0 = *(const float4*)&HS[(long long)iA0 * F + fl * 4];
      const float4 vA1 = *(const float4*)&HS[(long long)iA1 * F + fl * 4];
      const float4 vB0 = *(const float4*)&HS[(long long)iB0 * F + fl * 4];
      const float4 vB1 = *(const float4*)&HS[(long long)iB1 * F + fl * 4];
      if (e0 < cntA) {
        accA.x += vA0.x; accA.y += vA0.y; accA.z += vA0.z; accA.w += vA0.w;
      }
      if (e1 < cntA) {
        accA.x += vA1.x; accA.y += vA1.y; accA.z += vA1.z; accA.w += vA1.w;
      }
      if (e0 < cntB) {
        accB.x += vB0.x; accB.y += vB0.y; accB.z += vB0.z; accB.w += vB0.w;
      }
      if (e1 < cntB) {
        accB.x += vB1.x; accB.y += vB1.y; accB.z += vB1.z; accB.w += vB1.w;
      }
    }
    #pragma unroll
    for (int m = LPE; m < 64; m <<= 1) {
      accA.x += __shfl_xor(accA.x, m, 64);
      accA.y += __shfl_xor(accA.y, m, 64);
      accA.z += __shfl_xor(accA.z, m, 64);
      accA.w += __shfl_xor(accA.w, m, 64);
      accB.x += __shfl_xor(accB.x, m, 64);
      accB.y += __shfl_xor(accB.y, m, 64);
      accB.z += __shfl_xor(accB.z, m, 64);
      accB.w += __shfl_xor(accB.w, m, 64);
    }
    float4 rA, rB;
    rA.x = fmaf(diA, accA.x, bf.x); rA.y = fmaf(diA, accA.y, bf.y);
    rA.z = fmaf(diA, accA.z, bf.z); rA.w = fmaf(diA, accA.w, bf.w);
    rB.x = fmaf(diB, accB.x, bf.x); rB.y = fmaf(diB, accB.y, bf.y);
    rB.z = fmaf(diB, accB.z, bf.z); rB.w = fmaf(diB, accB.w, bf.w);
    if (RELU_OUT) {
      rA.x = fmaxf(rA.x, 0.f); rA.y = fmaxf(rA.y, 0.f);
      rA.z = fmaxf(rA.z, 0.f); rA.w = fmaxf(rA.w, 0.f);
      rB.x = fmaxf(rB.x, 0.f); rB.y = fmaxf(rB.y, 0.f);
      rB.z = fmaxf(rB.z, 0.f); rB.w = fmaxf(rB.w, 0.f);
    }
    if (!FUSE_W3) {
      if (g == 0) *(float4*)&out[dA * F + fl * 4] = rA;
      if (g == 1 && hasB) *(float4*)&out[dB * F + fl * 4] = rB;
    } else {
      float tA0 = rA.x * w3a0 + rA.y * w3a1 + rA.z * w3a2 + rA.w * w3a3;
      float tA1 = rA.x * w3b0 + rA.y * w3b1 + rA.z * w3b2 + rA.w * w3b3;
      float tB0 = rB.x * w3a0 + rB.y * w3a1 + rB.z * w3a2 + rB.w * w3a3;
      float tB1 = rB.x * w3b0 + rB.y * w3b1 + rB.z * w3b2 + rB.w * w3b3;
      #pragma unroll
      for (int m = 1; m < LPE; m <<= 1) {
        tA0 += __shfl_xor(tA0, m, 64);
        tA1 += __shfl_xor(tA1, m, 64);
        tB0 += __shfl_xor(tB0, m, 64);
        tB1 += __shfl_xor(tB1, m, 64);
      }
      if (lane == 0) {
        out[dA * 2 + 0] = diA * tA0;
        out[dA * 2 + 1] = diA * tA1;
      }
      if (lane == LPE && hasB) {
        out[dB * 2 + 0] = diB * tB0;
        out[dB * 2 + 1] = diB * tB1;
      }
    }
  }
}

// scalar aggregate for tiny F (layer 3, F=2)
template <int F, bool RELU_OUT>
__global__ __launch_bounds__(256) void k_aggregate(const float* __restrict__ HS,
                                                   const float* __restrict__ dinv,
                                                   const int* __restrict__ offsets,
                                                   const int* __restrict__ counts,
                                                   const int* __restrict__ elist,
                                                   const float* __restrict__ bias,
                                                   float* __restrict__ out, int n) {
  const int f = threadIdx.x % F;
  const int grp = threadIdx.x / F;
  constexpr int GRPS = 256 / F;
  const float bf = bias[f];

  for (long long d = (long long)blockIdx.x * GRPS + grp; d < n;
       d += (long long)gridDim.x * GRPS) {
    const float di = dinv[d];
    float acc = HS[d * F + f];
    const int start = offsets[d];
    const int cnt = counts[d];
    for (int j = 0; j < cnt; j += 8) {
      int idx[8];
      float v[8];
      #pragma unroll
      for (int t = 0; t < 8; ++t) {
        const int jj = (j + t < cnt) ? (j + t) : j;
        idx[t] = elist[start + jj];
      }
      #pragma unroll
      for (int t = 0; t < 8; ++t) v[t] = HS[(long long)idx[t] * F + f];
      #pragma unroll
      for (int t = 0; t < 8; ++t) acc += (j + t < cnt) ? v[t] : 0.f;
    }
    float r = fmaf(di, acc, bf);
    if (RELU_OUT) r = fmaxf(r, 0.f);
    out[d * F + f] = r;
  }
}

extern "C" void kernel_launch(void* const* d_in, const int* in_sizes, int n_in,
                              void* d_out, int out_size, void* d_ws, size_t ws_size,
                              hipStream_t stream) {
  const float* x = (const float*)d_in[0];
  const void* eraw = d_in[1];
  const float* W1 = (const float*)d_in[2];
  const float* b1 = (const float*)d_in[3];
  const float* W2 = (const float*)d_in[4];
  const float* b2 = (const float*)d_in[5];
  const float* W3 = (const float*)d_in[6];
  const float* b3 = (const float*)d_in[7];
  float* out = (float*)d_out;

  const int N = in_sizes[0] / 128;  // 100000
  const int E = in_sizes[1] / 2;    // 600000

  char* ws = (char*)d_ws;
  size_t off = 0;
  auto alloc = [&](size_t bytes) -> char* {
    char* p = ws + off;
    off = (off + bytes + 255) & ~(size_t)255;
    return p;
  };
  int*   counts   = (int*)alloc((size_t)N * 4 + 16);
  int*   scanned  = (int*)alloc((size_t)N * 4);
  int*   partials = (int*)alloc(1024 * 4);
  int*   offsets  = (int*)alloc((size_t)N * 4);
  int*   cursor   = (int*)alloc((size_t)N * 4);
  int*   srcn     = (int*)alloc((size_t)E * 4);
  int*   dstn     = (int*)alloc((size_t)E * 4);
  int*   elist    = (int*)alloc((size_t)E * 4);
  float* dinv     = (float*)alloc((size_t)N * 4);
  short* Wh1      = (short*)alloc(4 * 4 * 64 * 8 * 2);
  short* Wl1      = (short*)alloc(4 * 4 * 64 * 8 * 2);
  short* Wh2      = (short*)alloc(2 * 2 * 64 * 8 * 2);
  short* Wl2      = (short*)alloc(2 * 2 * 64 * 8 * 2);
  float* hbuf     = (float*)alloc((size_t)N * 64 * 4);  // hs1; later hs3 [N,2]
  float* h2buf    = (float*)alloc((size_t)N * 32 * 4);  // hs2 [N,32]
  (void)ws_size; (void)n_in; (void)out_size;

  // ---- CSR build + W pre-pack (zero+prepW+normalize fused) ----
  k_init<<<1184, 256, 0, stream>>>(counts, (N + 3) / 4, eraw, E, srcn, dstn,
                                   W1, W2, Wh1, Wl1, Wh2, Wl2);
  k_hist<<<FULL_GRID, 256, 0, stream>>>(dstn, E, N, counts);
  const int NB = (N + 1023) >> 10;
  k_scan1<<<NB, 1024, 0, stream>>>(counts, scanned, partials, N);
  k_scan3<<<(N + 255) / 256, 256, 0, stream>>>(scanned, partials, NB, counts,
                                               offsets, cursor, dinv, N);
  k_fill<<<FULL_GRID, 256, 0, stream>>>(srcn, dstn, E, N, cursor, elist);

  // ---- layer 1 transform: hs1 = dinv.*(x@W1) ----
  k_transform_mfma<128, 64><<<(N + 63) / 64, 256, 0, stream>>>(
      x, Wh1, Wl1, dinv, hbuf, N);
  // ---- FUSED layer-1 aggregate + layer-2 transform: -> hs2 ----
  k_agg1_t2<<<(N + 63) / 64, 256, 0, stream>>>(
      hbuf, dinv, offsets, counts, elist, b1, Wh2, Wl2, h2buf, N);
  // ---- layer-2 aggregate + ReLU + fused W3 -> hs3 ----
  k_agg_vec2<32, true, true><<<FULL_GRID, 256, 0, stream>>>(
      h2buf, dinv, offsets, counts, elist, b2, W3, hbuf, N);
  // ---- layer 3: agg hs3 + ReLU -> out ----
  k_aggregate<2, true><<<(N + 127) / 128, 256, 0, stream>>>(
      hbuf, dinv, offsets, counts, elist, b3, out, N);
}

// Round 16
// 168.803 us; speedup vs baseline: 3.6049x; 1.1511x over previous
//
#include <hip/hip_runtime.h>
#include <math.h>

// ---------------------------------------------------------------------------
// GCNEncoder: 3 stacked GCNConv layers (symmetric norm, self-loops) + ReLU.
//   R16 = R12 (proven best, 171.1us) + R13/R15's merged k_init (proven safe).
//   R13 (bf16 aggs), R14 (coop grid.sync), R15 (agg1+t2 fusion) all regressed
//   and are reverted. Structure:
//     - k_init: zero counts + prep W frags + normalize edges (per-block
//       dtype detect), one launch.
//     - XCD-partitioned hist/fill; block-scan + fused partial-scan.
//     - transforms: 3-term bf16-split MFMA (h = xh@Wh + xh@Wl + xl@Wh).
//     - aggregates: edge-group-parallel fp32, two nodes per wave, W3 fused
//       into agg2 via shuffle reduce.
// ---------------------------------------------------------------------------

#define FULL_GRID 2048
#define PARTS 8

typedef const __attribute__((address_space(1))) void* gas_ptr;
typedef __attribute__((address_space(3))) void* las_ptr;
typedef __attribute__((ext_vector_type(8))) short bf16x8;
typedef __attribute__((ext_vector_type(4))) float f32x4;

__device__ __forceinline__ void gld16(const void* g, void* l) {
  __builtin_amdgcn_global_load_lds((gas_ptr)g, (las_ptr)l, 16, 0, 0);
}

__device__ __forceinline__ unsigned short f2bf(float f) {  // RNE fp32->bf16
  unsigned int u = __float_as_uint(f);
  u += 0x7FFF + ((u >> 16) & 1);
  return (unsigned short)(u >> 16);
}
__device__ __forceinline__ float bf2f(unsigned short h) {
  return __uint_as_float(((unsigned int)h) << 16);
}

// blocks 0..127: zero counts; 128..159: prep W frags; 160..1183: normalize
// edges (per-block dtype detect on the global prefix -- no flag dependency).
__global__ __launch_bounds__(256) void k_init(int* __restrict__ p, int n4,
                                              const void* __restrict__ eraw, int E,
                                              int* __restrict__ srcn,
                                              int* __restrict__ dstn,
                                              const float* __restrict__ W1,
                                              const float* __restrict__ W2,
                                              short* __restrict__ Wh1,
                                              short* __restrict__ Wl1,
                                              short* __restrict__ Wh2,
                                              short* __restrict__ Wl2) {
  const int b = blockIdx.x;
  if (b < 128) {  // zero counts
    int i = b * blockDim.x + threadIdx.x;
    const int stride = 128 * blockDim.x;
    int4* p4 = (int4*)p;
    for (; i < n4; i += stride) p4[i] = make_int4(0, 0, 0, 0);
    return;
  }
  if (b < 160) {  // W fragment prep (32 blocks)
    const int t = (b - 128) * 256 + threadIdx.x;
    const int stride = 32 * 256;
    for (int q = t; q < 4 * 4 * 64 * 8; q += stride) {  // W1: KT=4, NT=4
      const int e = q & 7, lane = (q >> 3) & 63, nt = (q >> 9) & 3, kt = q >> 11;
      const int k = kt * 32 + (lane >> 4) * 8 + e;
      const int nn = nt * 16 + (lane & 15);
      const float f = W1[k * 64 + nn];
      const unsigned short h = f2bf(f);
      Wh1[q] = (short)h;
      Wl1[q] = (short)f2bf(f - bf2f(h));
    }
    for (int q = t; q < 2 * 2 * 64 * 8; q += stride) {  // W2: KT=2, NT=2
      const int e = q & 7, lane = (q >> 3) & 63, nt = (q >> 9) & 1, kt = q >> 10;
      const int k = kt * 32 + (lane >> 4) * 8 + e;
      const int nn = nt * 16 + (lane & 15);
      const float f = W2[k * 32 + nn];
      const unsigned short h = f2bf(f);
      Wh2[q] = (short)h;
      Wl2[q] = (short)f2bf(f - bf2f(h));
    }
    return;
  }
  // normalize with per-block dtype detect (odd 32-bit words of an int64
  // prefix are all zero iff edges are int64 with values < 2^31).
  __shared__ int sm[256];
  const unsigned int* words = (const unsigned int*)eraw;
  sm[threadIdx.x] = (words[threadIdx.x * 2 + 1] == 0u) ? 1 : 0;
  __syncthreads();
  for (int off = 128; off > 0; off >>= 1) {
    if (threadIdx.x < off) sm[threadIdx.x] += sm[threadIdx.x + off];
    __syncthreads();
  }
  const int is64 = sm[0] > 128;
  const int nb = b - 160;
  int i = nb * 256 + threadIdx.x;
  const int stride = 1024 * 256;
  if (is64) {
    const long long* e = (const long long*)eraw;
    for (; i < E; i += stride) {
      srcn[i] = (int)e[i];
      dstn[i] = (int)e[(long long)E + i];
    }
  } else {
    const int* e = (const int*)eraw;
    for (; i < E; i += stride) {
      srcn[i] = e[i];
      dstn[i] = e[E + i];
    }
  }
}

// XCD-partitioned histogram (partition p = blockIdx&7 -> dst range [lo,hi)).
__global__ __launch_bounds__(256) void k_hist(const int* __restrict__ dstn, int E,
                                              int N, int* __restrict__ counts) {
  const int part = blockIdx.x & (PARTS - 1);
  const int lo = (int)((long long)N * part / PARTS);
  const int hi = (int)((long long)N * (part + 1) / PARTS);
  int i = (blockIdx.x >> 3) * blockDim.x + threadIdx.x;
  const int stride = (gridDim.x >> 3) * blockDim.x;
  for (; i < E; i += stride) {
    const int d = dstn[i];
    if (d >= lo && d < hi) atomicAdd(&counts[d], 1);
  }
}

__global__ __launch_bounds__(1024) void k_scan1(const int* __restrict__ counts,
                                                int* __restrict__ scanned,
                                                int* __restrict__ partials, int n) {
  __shared__ int sm[1024];
  const int i = blockIdx.x * 1024 + threadIdx.x;
  const int v = (i < n) ? counts[i] : 0;
  sm[threadIdx.x] = v;
  __syncthreads();
  for (int off = 1; off < 1024; off <<= 1) {
    int t = sm[threadIdx.x];
    int u = (threadIdx.x >= off) ? sm[threadIdx.x - off] : 0;
    __syncthreads();
    sm[threadIdx.x] = t + u;
    __syncthreads();
  }
  const int inc = sm[threadIdx.x];
  if (i < n) scanned[i] = inc - v;  // exclusive within block
  if (threadIdx.x == 1023) partials[blockIdx.x] = inc;  // block total
}

__global__ __launch_bounds__(256) void k_scan3(const int* __restrict__ scanned,
                                               const int* __restrict__ partials,
                                               int nb,
                                               const int* __restrict__ counts,
                                               int* __restrict__ offsets,
                                               int* __restrict__ cursor,
                                               float* __restrict__ dinv, int n) {
  __shared__ int ps[1024];
  for (int t = threadIdx.x; t < nb; t += 256) ps[t] = partials[t];
  __syncthreads();
  if (threadIdx.x == 0) {
    int run = 0;
    for (int b = 0; b < nb; ++b) { const int v = ps[b]; ps[b] = run; run += v; }
  }
  __syncthreads();
  int i = blockIdx.x * blockDim.x + threadIdx.x;
  const int stride = gridDim.x * blockDim.x;
  for (; i < n; i += stride) {
    const int o = scanned[i] + ps[i >> 10];
    offsets[i] = o;
    cursor[i] = o;
    dinv[i] = rsqrtf((float)counts[i] + 1.0f);  // +1 self-loop
  }
}

// XCD-partitioned fill.
__global__ __launch_bounds__(256) void k_fill(const int* __restrict__ srcn,
                                              const int* __restrict__ dstn, int E,
                                              int N, int* __restrict__ cursor,
                                              int* __restrict__ elist) {
  const int part = blockIdx.x & (PARTS - 1);
  const int lo = (int)((long long)N * part / PARTS);
  const int hi = (int)((long long)N * (part + 1) / PARTS);
  int i = (blockIdx.x >> 3) * blockDim.x + threadIdx.x;
  const int stride = (gridDim.x >> 3) * blockDim.x;
  for (; i < E; i += stride) {
    const int d = dstn[i];
    if (d >= lo && d < hi) elist[atomicAdd(&cursor[d], 1)] = srcn[i];
  }
}

// hs = dinv .* (X @ W) via 3-term bf16-split MFMA (R11/R12-proven, fp32 out).
template <int F_IN, int F_OUT>
__global__ __launch_bounds__(256) void k_transform_mfma(
    const float* __restrict__ X, const short* __restrict__ Wh,
    const short* __restrict__ Wl, const float* __restrict__ dinv,
    float* __restrict__ H, int n) {
  constexpr int KT = F_IN / 32;
  constexpr int NT = F_OUT / 16;
  constexpr int K4f = F_IN / 4;
  constexpr int SLOTS = F_IN / 8;
  constexpr int TILE_M = 64;
  constexpr int WFRAG = KT * NT * 64 * 8;
  static_assert((WFRAG * 2) % 1024 == 0, "W segs");

  __shared__ __align__(16) unsigned short Xh[TILE_M * F_IN];
  __shared__ __align__(16) unsigned short Xl[TILE_M * F_IN];
  __shared__ __align__(16) unsigned short Whs[WFRAG];
  __shared__ __align__(16) unsigned short Wls[WFRAG];

  const int tid = threadIdx.x;
  const int lane = tid & 63;
  const int wid = tid >> 6;
  const long long base = (long long)blockIdx.x * TILE_M;

  constexpr int WSEGS = WFRAG * 2 / 1024;
  for (int seg = wid; seg < WSEGS; seg += 4) {
    gld16((const char*)Wh + seg * 1024 + lane * 16, (char*)Whs + seg * 1024);
    gld16((const char*)Wl + seg * 1024 + lane * 16, (char*)Wls + seg * 1024);
  }

  const float4* __restrict__ X4 = (const float4*)X;
  for (int g = tid; g < TILE_M * K4f; g += 256) {
    const int row = g / K4f, c4 = g % K4f;
    float4 v = make_float4(0.f, 0.f, 0.f, 0.f);
    if (base + row < n) v = X4[(base + row) * K4f + c4];
    ushort4 hv, lv;
    hv.x = f2bf(v.x); lv.x = f2bf(v.x - bf2f(hv.x));
    hv.y = f2bf(v.y); lv.y = f2bf(v.y - bf2f(hv.y));
    hv.z = f2bf(v.z); lv.z = f2bf(v.z - bf2f(hv.z));
    hv.w = f2bf(v.w); lv.w = f2bf(v.w - bf2f(hv.w));
    const int slot = (c4 >> 1) ^ (row & (SLOTS - 1));
    const int boff = row * (F_IN * 2) + slot * 16 + (c4 & 1) * 8;
    *(ushort4*)((char*)Xh + boff) = hv;
    *(ushort4*)((char*)Xl + boff) = lv;
  }
  __syncthreads();

  const int arow = lane & 15;
  const int kg = lane >> 4;
  const int lrow = wid * 16 + arow;

  f32x4 acc[NT];
  #pragma unroll
  for (int t = 0; t < NT; ++t) {
    f32x4 z = {0.f, 0.f, 0.f, 0.f};
    acc[t] = z;
  }

  #pragma unroll
  for (int kt = 0; kt < KT; ++kt) {
    const int slot = (kt * 4 + kg) ^ (lrow & (SLOTS - 1));
    const int aoff = lrow * (F_IN * 2) + slot * 16;
    const bf16x8 ah = *(const bf16x8*)((const char*)Xh + aoff);
    const bf16x8 al = *(const bf16x8*)((const char*)Xl + aoff);
    #pragma unroll
    for (int nt = 0; nt < NT; ++nt) {
      const int woff = ((kt * NT + nt) * 64 + lane) * 8;
      const bf16x8 bh = *(const bf16x8*)&Whs[woff];
      const bf16x8 bl = *(const bf16x8*)&Wls[woff];
      acc[nt] = __builtin_amdgcn_mfma_f32_16x16x32_bf16(ah, bh, acc[nt], 0, 0, 0);
      acc[nt] = __builtin_amdgcn_mfma_f32_16x16x32_bf16(ah, bl, acc[nt], 0, 0, 0);
      acc[nt] = __builtin_amdgcn_mfma_f32_16x16x32_bf16(al, bh, acc[nt], 0, 0, 0);
    }
  }

  #pragma unroll
  for (int r = 0; r < 4; ++r) {
    const long long row = base + wid * 16 + kg * 4 + r;
    if (row < n) {
      const float di = dinv[row];
      #pragma unroll
      for (int nt = 0; nt < NT; ++nt)
        H[row * F_OUT + nt * 16 + arow] = di * acc[nt][r];
    }
  }
}

// Edge-group-parallel aggregate, TWO nodes per wave (R12-proven, fp32).
template <int F, bool RELU_OUT, bool FUSE_W3>
__global__ __launch_bounds__(256) void k_agg_vec2(const float* __restrict__ HS,
                                                  const float* __restrict__ dinv,
                                                  const int* __restrict__ offsets,
                                                  const int* __restrict__ counts,
                                                  const int* __restrict__ elist,
                                                  const float* __restrict__ bias,
                                                  const float* __restrict__ W3,
                                                  float* __restrict__ out, int n) {
  constexpr int LPE = F / 4;
  constexpr int EPW = 64 / LPE;
  const int lane = threadIdx.x & 63;
  const int wv = (blockIdx.x * (blockDim.x >> 6)) + (threadIdx.x >> 6);
  const int nwaves = gridDim.x * (blockDim.x >> 6);
  const int g = lane / LPE;
  const int fl = lane % LPE;
  const float4 bf = *(const float4*)&bias[fl * 4];

  float w3a0 = 0.f, w3a1 = 0.f, w3a2 = 0.f, w3a3 = 0.f;
  float w3b0 = 0.f, w3b1 = 0.f, w3b2 = 0.f, w3b3 = 0.f;
  if (FUSE_W3) {
    w3a0 = W3[(fl * 4 + 0) * 2 + 0]; w3b0 = W3[(fl * 4 + 0) * 2 + 1];
    w3a1 = W3[(fl * 4 + 1) * 2 + 0]; w3b1 = W3[(fl * 4 + 1) * 2 + 1];
    w3a2 = W3[(fl * 4 + 2) * 2 + 0]; w3b2 = W3[(fl * 4 + 2) * 2 + 1];
    w3a3 = W3[(fl * 4 + 3) * 2 + 0]; w3b3 = W3[(fl * 4 + 3) * 2 + 1];
  }

  for (long long dA = wv; dA < n; dA += 2ll * nwaves) {
    const long long dB = dA + nwaves;
    const bool hasB = dB < n;
    const float diA = dinv[dA];
    const float diB = hasB ? dinv[dB] : 0.f;
    const int stA = offsets[dA];
    const int cntA = counts[dA];
    const int stB = hasB ? offsets[dB] : 0;
    const int cntB = hasB ? counts[dB] : 0;
    float4 accA = make_float4(0.f, 0.f, 0.f, 0.f);
    float4 accB = make_float4(0.f, 0.f, 0.f, 0.f);
    if (g == 0) accA = *(const float4*)&HS[dA * F + fl * 4];
    if (g == 1 && hasB) accB = *(const float4*)&HS[dB * F + fl * 4];

    const int jmax = cntA > cntB ? cntA : cntB;
    const int cA = cntA > 0 ? cntA - 1 : 0;
    const int cB = cntB > 0 ? cntB - 1 : 0;
    for (int j = 0; j < jmax; j += 2 * EPW) {
      const int e0 = j + g;
      const int e1 = j + EPW + g;
      const int iA0 = elist[stA + (e0 < cntA ? e0 : cA)];
      const int iA1 = elist[stA + (e1 < cntA ? e1 : cA)];
      const int iB0 = elist[stB + (e0 < cntB ? e0 : cB)];
      const int iB1 = elist[stB + (e1 < cntB ? e1 : cB)];
      const float4 vA0 = *(const float4*)&HS[(long long)iA0 * F + fl * 4];
      const float4 vA1 = *(const float4*)&HS[(long long)iA1 * F + fl * 4];
      const float4 vB0 = *(const float4*)&HS[(long long)iB0 * F + fl * 4];
      const float4 vB1 = *(const float4*)&HS[(long long)iB1 * F + fl * 4];
      if (e0 < cntA) {
        accA.x += vA0.x; accA.y += vA0.y; accA.z += vA0.z; accA.w += vA0.w;
      }
      if (e1 < cntA) {
        accA.x += vA1.x; accA.y += vA1.y; accA.z += vA1.z; accA.w += vA1.w;
      }
      if (e0 < cntB) {
        accB.x += vB0.x; accB.y += vB0.y; accB.z += vB0.z; accB.w += vB0.w;
      }
      if (e1 < cntB) {
        accB.x += vB1.x; accB.y += vB1.y; accB.z += vB1.z; accB.w += vB1.w;
      }
    }
    #pragma unroll
    for (int m = LPE; m < 64; m <<= 1) {
      accA.x += __shfl_xor(accA.x, m, 64);
      accA.y += __shfl_xor(accA.y, m, 64);
      accA.z += __shfl_xor(accA.z, m, 64);
      accA.w += __shfl_xor(accA.w, m, 64);
      accB.x += __shfl_xor(accB.x, m, 64);
      accB.y += __shfl_xor(accB.y, m, 64);
      accB.z += __shfl_xor(accB.z, m, 64);
      accB.w += __shfl_xor(accB.w, m, 64);
    }
    float4 rA, rB;
    rA.x = fmaf(diA, accA.x, bf.x); rA.y = fmaf(diA, accA.y, bf.y);
    rA.z = fmaf(diA, accA.z, bf.z); rA.w = fmaf(diA, accA.w, bf.w);
    rB.x = fmaf(diB, accB.x, bf.x); rB.y = fmaf(diB, accB.y, bf.y);
    rB.z = fmaf(diB, accB.z, bf.z); rB.w = fmaf(diB, accB.w, bf.w);
    if (RELU_OUT) {
      rA.x = fmaxf(rA.x, 0.f); rA.y = fmaxf(rA.y, 0.f);
      rA.z = fmaxf(rA.z, 0.f); rA.w = fmaxf(rA.w, 0.f);
      rB.x = fmaxf(rB.x, 0.f); rB.y = fmaxf(rB.y, 0.f);
      rB.z = fmaxf(rB.z, 0.f); rB.w = fmaxf(rB.w, 0.f);
    }
    if (!FUSE_W3) {
      if (g == 0) *(float4*)&out[dA * F + fl * 4] = rA;
      if (g == 1 && hasB) *(float4*)&out[dB * F + fl * 4] = rB;
    } else {
      float tA0 = rA.x * w3a0 + rA.y * w3a1 + rA.z * w3a2 + rA.w * w3a3;
      float tA1 = rA.x * w3b0 + rA.y * w3b1 + rA.z * w3b2 + rA.w * w3b3;
      float tB0 = rB.x * w3a0 + rB.y * w3a1 + rB.z * w3a2 + rB.w * w3a3;
      float tB1 = rB.x * w3b0 + rB.y * w3b1 + rB.z * w3b2 + rB.w * w3b3;
      #pragma unroll
      for (int m = 1; m < LPE; m <<= 1) {
        tA0 += __shfl_xor(tA0, m, 64);
        tA1 += __shfl_xor(tA1, m, 64);
        tB0 += __shfl_xor(tB0, m, 64);
        tB1 += __shfl_xor(tB1, m, 64);
      }
      if (lane == 0) {
        out[dA * 2 + 0] = diA * tA0;
        out[dA * 2 + 1] = diA * tA1;
      }
      if (lane == LPE && hasB) {
        out[dB * 2 + 0] = diB * tB0;
        out[dB * 2 + 1] = diB * tB1;
      }
    }
  }
}

// scalar aggregate for tiny F (layer 3, F=2)
template <int F, bool RELU_OUT>
__global__ __launch_bounds__(256) void k_aggregate(const float* __restrict__ HS,
                                                   const float* __restrict__ dinv,
                                                   const int* __restrict__ offsets,
                                                   const int* __restrict__ counts,
                                                   const int* __restrict__ elist,
                                                   const float* __restrict__ bias,
                                                   float* __restrict__ out, int n) {
  const int f = threadIdx.x % F;
  const int grp = threadIdx.x / F;
  constexpr int GRPS = 256 / F;
  const float bf = bias[f];

  for (long long d = (long long)blockIdx.x * GRPS + grp; d < n;
       d += (long long)gridDim.x * GRPS) {
    const float di = dinv[d];
    float acc = HS[d * F + f];
    const int start = offsets[d];
    const int cnt = counts[d];
    for (int j = 0; j < cnt; j += 8) {
      int idx[8];
      float v[8];
      #pragma unroll
      for (int t = 0; t < 8; ++t) {
        const int jj = (j + t < cnt) ? (j + t) : j;
        idx[t] = elist[start + jj];
      }
      #pragma unroll
      for (int t = 0; t < 8; ++t) v[t] = HS[(long long)idx[t] * F + f];
      #pragma unroll
      for (int t = 0; t < 8; ++t) acc += (j + t < cnt) ? v[t] : 0.f;
    }
    float r = fmaf(di, acc, bf);
    if (RELU_OUT) r = fmaxf(r, 0.f);
    out[d * F + f] = r;
  }
}

extern "C" void kernel_launch(void* const* d_in, const int* in_sizes, int n_in,
                              void* d_out, int out_size, void* d_ws, size_t ws_size,
                              hipStream_t stream) {
  const float* x = (const float*)d_in[0];
  const void* eraw = d_in[1];
  const float* W1 = (const float*)d_in[2];
  const float* b1 = (const float*)d_in[3];
  const float* W2 = (const float*)d_in[4];
  const float* b2 = (const float*)d_in[5];
  const float* W3 = (const float*)d_in[6];
  const float* b3 = (const float*)d_in[7];
  float* out = (float*)d_out;

  const int N = in_sizes[0] / 128;  // 100000
  const int E = in_sizes[1] / 2;    // 600000

  char* ws = (char*)d_ws;
  size_t off = 0;
  auto alloc = [&](size_t bytes) -> char* {
    char* p = ws + off;
    off = (off + bytes + 255) & ~(size_t)255;
    return p;
  };
  int*   counts   = (int*)alloc((size_t)N * 4 + 16);
  int*   scanned  = (int*)alloc((size_t)N * 4);
  int*   partials = (int*)alloc(1024 * 4);
  int*   offsets  = (int*)alloc((size_t)N * 4);
  int*   cursor   = (int*)alloc((size_t)N * 4);
  int*   srcn     = (int*)alloc((size_t)E * 4);
  int*   dstn     = (int*)alloc((size_t)E * 4);
  int*   elist    = (int*)alloc((size_t)E * 4);
  float* dinv     = (float*)alloc((size_t)N * 4);
  short* Wh1      = (short*)alloc(4 * 4 * 64 * 8 * 2);
  short* Wl1      = (short*)alloc(4 * 4 * 64 * 8 * 2);
  short* Wh2      = (short*)alloc(2 * 2 * 64 * 8 * 2);
  short* Wl2      = (short*)alloc(2 * 2 * 64 * 8 * 2);
  float* hbuf     = (float*)alloc((size_t)N * 64 * 4);  // hs1; later hs3 [N,2]
  float* obuf     = (float*)alloc((size_t)N * 64 * 4);  // out1 [N,64]
  float* h2buf    = (float*)alloc((size_t)N * 32 * 4);  // hs2 [N,32]
  (void)ws_size; (void)n_in; (void)out_size;

  // ---- CSR build + W pre-pack (zero+prepW+normalize fused) ----
  k_init<<<1184, 256, 0, stream>>>(counts, (N + 3) / 4, eraw, E, srcn, dstn,
                                   W1, W2, Wh1, Wl1, Wh2, Wl2);
  k_hist<<<FULL_GRID, 256, 0, stream>>>(dstn, E, N, counts);
  const int NB = (N + 1023) >> 10;
  k_scan1<<<NB, 1024, 0, stream>>>(counts, scanned, partials, N);
  k_scan3<<<(N + 255) / 256, 256, 0, stream>>>(scanned, partials, NB, counts,
                                               offsets, cursor, dinv, N);
  k_fill<<<FULL_GRID, 256, 0, stream>>>(srcn, dstn, E, N, cursor, elist);

  // ---- layer 1: hs1 = dinv.*(x@W1); out1 = relu(agg(hs1)) ----
  k_transform_mfma<128, 64><<<(N + 63) / 64, 256, 0, stream>>>(
      x, Wh1, Wl1, dinv, hbuf, N);
  k_agg_vec2<64, true, false><<<FULL_GRID, 256, 0, stream>>>(
      hbuf, dinv, offsets, counts, elist, b1, nullptr, obuf, N);

  // ---- layer 2: hs2 = dinv.*(out1@W2); agg + ReLU + fused W3 -> hs3 ----
  k_transform_mfma<64, 32><<<(N + 63) / 64, 256, 0, stream>>>(
      obuf, Wh2, Wl2, dinv, h2buf, N);
  k_agg_vec2<32, true, true><<<FULL_GRID, 256, 0, stream>>>(
      h2buf, dinv, offsets, counts, elist, b2, W3, hbuf, N);

  // ---- layer 3: agg hs3 + ReLU -> out ----
  k_aggregate<2, true><<<(N + 127) / 128, 256, 0, stream>>>(
      hbuf, dinv, offsets, counts, elist, b3, out, N);
}